// Round 14
// baseline (79.950 us; speedup 1.0000x reference)
//
#include <hip/hip_runtime.h>

typedef unsigned int uint32;
typedef unsigned short ushort16;
typedef __attribute__((ext_vector_type(16))) float f32x16;
typedef __attribute__((ext_vector_type(8)))  short short8;

#define THREADS 256
#define QB 128      // queries per block: 4 waves x 32 (FR=1)
#define JS 8        // j-slices -> 128x8x2 = 2048 blocks = 8/CU = 32 waves/CU
#define RB 128      // reduce stage-1 blocks

__device__ inline ushort16 bf16rn(float x) {
    uint32 u = __float_as_uint(x);
    u += 0x7FFFu + ((u >> 16) & 1u);
    return (ushort16)(u >> 16);
}
__device__ inline float bf2f(ushort16 h) { return __uint_as_float(((uint32)h) << 16); }

// K=16 slot map. Per coord c (4 slots): q:[h,h,m,m]  s:[bh,bm,bh,bm] where
// b=-2c -> dot contributes (h+m)(bh+bm) = -2*c_q*c_s + O(2^-17).
// Slots 12..14: q:[1,1,1], s: 3-level split of |p|^2. Slot 15: 0.
// Padded scan points: s12 = bf16(1e30) sentinel.
__device__ inline void prep_one(const float* __restrict__ P, int np, int i,
                                short8* __restrict__ Qf, short8* __restrict__ Sf,
                                float* __restrict__ a2)
{
    ushort16 qs[16], ss[16];
#pragma unroll
    for (int s = 0; s < 16; ++s) { qs[s] = 0; ss[s] = 0; }
    float w = 0.f;
    if (i < np) {
        float c[3] = {P[3*i], P[3*i+1], P[3*i+2]};
        w = fmaf(c[0], c[0], fmaf(c[1], c[1], c[2]*c[2]));
#pragma unroll
        for (int cc = 0; cc < 3; ++cc) {
            ushort16 h = bf16rn(c[cc]);
            ushort16 m = bf16rn(c[cc] - bf2f(h));
            float bv = -2.f * c[cc];
            ushort16 bh = bf16rn(bv);
            ushort16 bm = bf16rn(bv - bf2f(bh));
            const int b = 4*cc;
            qs[b]=h;  qs[b+1]=h;  qs[b+2]=m;  qs[b+3]=m;
            ss[b]=bh; ss[b+1]=bm; ss[b+2]=bh; ss[b+3]=bm;
        }
        qs[12]=0x3F80; qs[13]=0x3F80; qs[14]=0x3F80;
        ushort16 wh = bf16rn(w);
        float r1 = w - bf2f(wh);
        ushort16 wm = bf16rn(r1);
        ushort16 wl = bf16rn(r1 - bf2f(wm));
        ss[12]=wh; ss[13]=wm; ss[14]=wl;
    } else {
        ss[12] = bf16rn(1e30f);
    }
    a2[i] = w;
    const int row = i & 31, grp = i >> 5;
#pragma unroll
    for (int h = 0; h < 2; ++h) {
        short8 qv, sv;
#pragma unroll
        for (int e = 0; e < 8; ++e) { qv[e] = (short)qs[8*h+e]; sv[e] = (short)ss[8*h+e]; }
        Qf[(size_t)grp*64 + h*32 + row] = qv;
        Sf[(size_t)grp*64 + h*32 + row] = sv;
    }
}

__global__ __launch_bounds__(THREADS) void cd_prep(
    const float* __restrict__ A, int n, int padN,
    const float* __restrict__ B, int m, int padM,
    short8* QfA, short8* SfA, float* a2A,
    short8* QfB, short8* SfB, float* a2B,
    uint32* bits)
{
    const int i = blockIdx.x * THREADS + threadIdx.x;
    if (i < n + m) bits[i] = 0x7F800000u;  // +inf
    if (i < padN) prep_one(A, n, i, QfA, SfA, a2A);
    if (i < padM) prep_one(B, m, i, QfB, SfB, a2B);
}

// xor-equivalent DPP butterfly step: returns min(v, perm(v)). Pure VALU.
__device__ inline float dppmin(float v, int ctrl) {
    float s;
    switch (ctrl) {
        case 0xB1:  s = __int_as_float(__builtin_amdgcn_mov_dpp(__float_as_int(v), 0xB1,  0xf, 0xf, false)); break; // xor1
        case 0x4E:  s = __int_as_float(__builtin_amdgcn_mov_dpp(__float_as_int(v), 0x4E,  0xf, 0xf, false)); break; // xor2
        case 0x141: s = __int_as_float(__builtin_amdgcn_mov_dpp(__float_as_int(v), 0x141, 0xf, 0xf, false)); break; // half_mirror
        default:    s = __int_as_float(__builtin_amdgcn_mov_dpp(__float_as_int(v), 0x140, 0xf, 0xf, false)); break; // row_mirror
    }
    return fminf(v, s);
}

// 32x32x16 MFMA chamfer pass, 8-waves/SIMD config (<=64 VGPR target):
// FR=1 (32 queries/wave, av=4 regs), single-tile fold (result consumed
// immediately), 3-deep register prefetch, running pointer. No LDS (Sf is
// 512 KB, L2-resident). Column-min via DPP butterfly + one xor16 shuffle.
// C layout (m74/m101): col=lane&31, row=(reg&3)+8*(reg>>2)+4*(lane>>5).
// a2 added at tail; atomicMin on float bits (order-independent).
__global__ __launch_bounds__(THREADS, 8) void cd_mfma(
    const short8* __restrict__ QfA, const short8* __restrict__ SfA,
    const float* __restrict__ a2A, int padN, int n,
    const short8* __restrict__ QfB, const short8* __restrict__ SfB,
    const float* __restrict__ a2B, int padM, int m,
    uint32* __restrict__ bits)
{
    const short8* Qf; const short8* Sf; const float* a2; uint32* outb;
    int nq, padQ, padS;
    if (blockIdx.z == 0) { Qf=QfA; a2=a2A; nq=n; padQ=padN; Sf=SfB; padS=padM; outb=bits;   }
    else                 { Qf=QfB; a2=a2B; nq=m; padQ=padM; Sf=SfA; padS=padN; outb=bits+n; }

    if ((int)(blockIdx.x * QB) >= padQ) return;
    const int ntiles = padS >> 5;
    const int tps = (ntiles + JS - 1) / JS;
    const int t0 = blockIdx.y * tps;
    const int t1 = min(t0 + tps, ntiles);
    if (t0 >= t1) return;

    const int tid = threadIdx.x, lane = tid & 63, wid = tid >> 6;
    const int qbase = blockIdx.x * QB + wid * 32;

    const short8 av = Qf[(size_t)(qbase >> 5) * 64 + lane];

    float rmin[16];
#pragma unroll
    for (int r = 0; r < 16; ++r) rmin[r] = 1e30f;

    const f32x16 zero = {0.f,0.f,0.f,0.f,0.f,0.f,0.f,0.f,
                         0.f,0.f,0.f,0.f,0.f,0.f,0.f,0.f};

    const int nt = t1 - t0;
    const short8* p = Sf + (size_t)t0 * 64 + lane;

    // 3-deep register prefetch
    short8 c0 = p[0];
    short8 c1 = (nt > 1) ? p[64] : c0;
    short8 c2 = (nt > 2) ? p[128] : c0;
    p += 192;

    for (int it = 0; it < nt; ++it) {
        const short8 b = c0;
        c0 = c1; c1 = c2;
        if (it + 3 < nt) { c2 = p[0]; p += 64; }
        const f32x16 c = __builtin_amdgcn_mfma_f32_32x32x16_bf16(av, b, zero, 0, 0, 0);
#pragma unroll
        for (int r = 0; r < 16; ++r) rmin[r] = fminf(rmin[r], c[r]);
    }

    // min over the 32 columns: 4 DPP steps (VALU) -> 16-group min in every
    // lane, then one xor16 shuffle -> full 32-half min in every lane.
#pragma unroll
    for (int r = 0; r < 16; ++r) {
        float v = rmin[r];
        v = dppmin(v, 0xB1);
        v = dppmin(v, 0x4E);
        v = dppmin(v, 0x141);
        v = dppmin(v, 0x140);
        v = fminf(v, __shfl_xor(v, 16, 64));
        rmin[r] = v;
    }

    if ((lane & 31) == 0) {
        const int h4 = (lane >> 5) * 4;
#pragma unroll
        for (int qq = 0; qq < 4; ++qq) {
            const int rowb = qbase + 8*qq + h4;
            const float4 aa = *(const float4*)(a2 + rowb);
            const float av4[4] = {aa.x, aa.y, aa.z, aa.w};
#pragma unroll
            for (int e = 0; e < 4; ++e) {
                const int qi = rowb + e;
                if (qi < nq) {
                    const float sq = fmaxf(rmin[4*qq + e] + av4[e], 0.f);
                    atomicMin(&outb[qi], __float_as_uint(sq));
                }
            }
        }
    }
}

__global__ __launch_bounds__(THREADS) void cd_reduce1(
    const uint32* __restrict__ bits, int count, double* __restrict__ partials)
{
    double s = 0.0;
    for (int i = blockIdx.x * THREADS + threadIdx.x; i < count; i += gridDim.x * THREADS)
        s += (double)sqrtf(__uint_as_float(bits[i]));
#pragma unroll
    for (int off = 32; off; off >>= 1) s += __shfl_down(s, off, 64);
    __shared__ double sw[4];
    const int lane = threadIdx.x & 63, wid = threadIdx.x >> 6;
    if (lane == 0) sw[wid] = s;
    __syncthreads();
    if (threadIdx.x == 0) partials[blockIdx.x] = sw[0] + sw[1] + sw[2] + sw[3];
}

__global__ __launch_bounds__(THREADS) void cd_reduce2(
    const double* __restrict__ partials, int nb, int total, float* __restrict__ out)
{
    double s = 0.0;
    for (int i = threadIdx.x; i < nb; i += THREADS) s += partials[i];
#pragma unroll
    for (int off = 32; off; off >>= 1) s += __shfl_down(s, off, 64);
    __shared__ double sw[4];
    const int lane = threadIdx.x & 63, wid = threadIdx.x >> 6;
    if (lane == 0) sw[wid] = s;
    __syncthreads();
    if (threadIdx.x == 0)
        out[0] = (float)((sw[0] + sw[1] + sw[2] + sw[3]) / (double)total);
}

extern "C" void kernel_launch(void* const* d_in, const int* in_sizes, int n_in,
                              void* d_out, int out_size, void* d_ws, size_t ws_size,
                              hipStream_t stream) {
    const float* a = (const float*)d_in[0];
    const float* b = (const float*)d_in[1];
    const int n = in_sizes[0] / 3;
    const int m = in_sizes[1] / 3;
    const int total = n + m;
    float* out = (float*)d_out;

    const int padN = (n + QB - 1) / QB * QB;
    const int padM = (m + QB - 1) / QB * QB;

    // ws: QfA | SfA | a2A | QfB | SfB | a2B | bits | partials
    char* wp = (char*)d_ws;
    short8* QfA = (short8*)wp;   wp += (size_t)padN * 64;
    short8* SfA = (short8*)wp;   wp += (size_t)padN * 64;
    float*  a2A = (float*)wp;    wp += (size_t)padN * 4;
    short8* QfB = (short8*)wp;   wp += (size_t)padM * 64;
    short8* SfB = (short8*)wp;   wp += (size_t)padM * 64;
    float*  a2B = (float*)wp;    wp += (size_t)padM * 4;
    uint32* bits = (uint32*)wp;  wp += (size_t)total * 4;
    wp = (char*)(((size_t)wp + 255) & ~(size_t)255);
    double* partials = (double*)wp;

    const int prepElems = max(max(padN, padM), total);
    cd_prep<<<(prepElems + THREADS - 1) / THREADS, THREADS, 0, stream>>>(
        a, n, padN, b, m, padM, QfA, SfA, a2A, QfB, SfB, a2B, bits);

    const int gx = max(padN, padM) / QB;
    dim3 grid(gx, JS, 2);
    cd_mfma<<<grid, THREADS, 0, stream>>>(QfA, SfA, a2A, padN, n,
                                          QfB, SfB, a2B, padM, m, bits);

    cd_reduce1<<<RB, THREADS, 0, stream>>>(bits, total, partials);
    cd_reduce2<<<1, THREADS, 0, stream>>>(partials, RB, total, out);
}

// Round 15
// 39.973 us; speedup vs baseline: 2.0001x; 2.0001x over previous
//
#include <hip/hip_runtime.h>

typedef unsigned int uint32;
typedef unsigned short ushort16;
typedef __attribute__((ext_vector_type(16))) float f32x16;
typedef __attribute__((ext_vector_type(8)))  short short8;

#define THREADS 256
#define QB 128      // queries per block: 4 waves x 32 (FR=1)
#define CH 8        // 32-point tiles per LDS chunk (8 KB/buf, 16 KB dbuf)
#define JS 8        // j-slices -> 128x8x2 = 2048 blocks = 8/CU
#define RB 64       // reduce stage-1 blocks

__device__ inline ushort16 bf16rn(float x) {
    uint32 u = __float_as_uint(x);
    u += 0x7FFFu + ((u >> 16) & 1u);
    return (ushort16)(u >> 16);
}
__device__ inline float bf2f(ushort16 h) { return __uint_as_float(((uint32)h) << 16); }

// K=16 slot map. Per coord c (4 slots): q:[h,h,m,m]  s:[bh,bm,bh,bm] where
// b=-2c -> dot contributes (h+m)(bh+bm) = -2*c_q*c_s + O(2^-17).
// Slots 12..14: q:[1,1,1], s: 3-level split of |p|^2. Slot 15: 0.
// Padded scan points: s12 = bf16(1e30) sentinel.
__device__ inline void prep_one(const float* __restrict__ P, int np, int i,
                                short8* __restrict__ Qf, short8* __restrict__ Sf,
                                float* __restrict__ a2)
{
    ushort16 qs[16], ss[16];
#pragma unroll
    for (int s = 0; s < 16; ++s) { qs[s] = 0; ss[s] = 0; }
    float w = 0.f;
    if (i < np) {
        float c[3] = {P[3*i], P[3*i+1], P[3*i+2]};
        w = fmaf(c[0], c[0], fmaf(c[1], c[1], c[2]*c[2]));
#pragma unroll
        for (int cc = 0; cc < 3; ++cc) {
            ushort16 h = bf16rn(c[cc]);
            ushort16 m = bf16rn(c[cc] - bf2f(h));
            float bv = -2.f * c[cc];
            ushort16 bh = bf16rn(bv);
            ushort16 bm = bf16rn(bv - bf2f(bh));
            const int b = 4*cc;
            qs[b]=h;  qs[b+1]=h;  qs[b+2]=m;  qs[b+3]=m;
            ss[b]=bh; ss[b+1]=bm; ss[b+2]=bh; ss[b+3]=bm;
        }
        qs[12]=0x3F80; qs[13]=0x3F80; qs[14]=0x3F80;
        ushort16 wh = bf16rn(w);
        float r1 = w - bf2f(wh);
        ushort16 wm = bf16rn(r1);
        ushort16 wl = bf16rn(r1 - bf2f(wm));
        ss[12]=wh; ss[13]=wm; ss[14]=wl;
    } else {
        ss[12] = bf16rn(1e30f);
    }
    a2[i] = w;
    const int row = i & 31, grp = i >> 5;
#pragma unroll
    for (int h = 0; h < 2; ++h) {
        short8 qv, sv;
#pragma unroll
        for (int e = 0; e < 8; ++e) { qv[e] = (short)qs[8*h+e]; sv[e] = (short)ss[8*h+e]; }
        Qf[(size_t)grp*64 + h*32 + row] = qv;
        Sf[(size_t)grp*64 + h*32 + row] = sv;
    }
}

__global__ __launch_bounds__(THREADS) void cd_prep(
    const float* __restrict__ A, int n, int padN,
    const float* __restrict__ B, int m, int padM,
    short8* QfA, short8* SfA, float* a2A,
    short8* QfB, short8* SfB, float* a2B,
    uint32* bits)
{
    const int i = blockIdx.x * THREADS + threadIdx.x;
    if (i < n + m) bits[i] = 0x7F800000u;  // +inf
    if (i < padN) prep_one(A, n, i, QfA, SfA, a2A);
    if (i < padM) prep_one(B, m, i, QfB, SfB, a2B);
}

// xor-equivalent DPP butterfly step: returns min(v, perm(v)). Pure VALU.
__device__ inline float dppmin(float v, int ctrl) {
    float s;
    switch (ctrl) {
        case 0xB1:  s = __int_as_float(__builtin_amdgcn_mov_dpp(__float_as_int(v), 0xB1,  0xf, 0xf, false)); break; // xor1
        case 0x4E:  s = __int_as_float(__builtin_amdgcn_mov_dpp(__float_as_int(v), 0x4E,  0xf, 0xf, false)); break; // xor2
        case 0x141: s = __int_as_float(__builtin_amdgcn_mov_dpp(__float_as_int(v), 0x141, 0xf, 0xf, false)); break; // half_mirror
        default:    s = __int_as_float(__builtin_amdgcn_mov_dpp(__float_as_int(v), 0x140, 0xf, 0xf, false)); break; // row_mirror
    }
    return fminf(v, s);
}

// 32x32x16 MFMA chamfer pass. FR=1 (32 queries/wave), 2048 blocks (8/CU),
// launch_bounds(256,4): ~94 VGPR live, no spill, ~5 waves/SIMD. C operand is
// preloaded with the a^2-row broadcast (replaces the zero bank 1:1 and kills
// the tail a^2 pass): D = a^2 + |p|^2 - 2 a.p directly. Two tiles in flight
// (32 result regs) so fold(t) overlaps MFMA issue(t+1). LDS double-buffered,
// issue-early/write-late staging. Column-min via DPP butterfly + one xor16
// shuffle; atomicMin on float bits (order-independent => deterministic).
// C layout (m74/m101): col=lane&31, row=(reg&3)+8*(reg>>2)+4*(lane>>5).
__global__ __launch_bounds__(THREADS, 4) void cd_mfma(
    const short8* __restrict__ QfA, const short8* __restrict__ SfA,
    const float* __restrict__ a2A, int padN, int n,
    const short8* __restrict__ QfB, const short8* __restrict__ SfB,
    const float* __restrict__ a2B, int padM, int m,
    uint32* __restrict__ bits)
{
    __shared__ short8 sb[2][CH*64];

    const short8* Qf; const short8* Sf; const float* a2; uint32* outb;
    int nq, padQ, padS;
    if (blockIdx.z == 0) { Qf=QfA; a2=a2A; nq=n; padQ=padN; Sf=SfB; padS=padM; outb=bits;   }
    else                 { Qf=QfB; a2=a2B; nq=m; padQ=padM; Sf=SfA; padS=padN; outb=bits+n; }

    if ((int)(blockIdx.x * QB) >= padQ) return;
    const int ntiles = padS >> 5;
    const int tps = ((ntiles + JS*CH - 1) / (JS*CH)) * CH;
    const int t0 = blockIdx.y * tps;
    const int t1 = min(t0 + tps, ntiles);
    if (t0 >= t1) return;

    const int tid = threadIdx.x, lane = tid & 63, wid = tid >> 6;
    const int qbase = blockIdx.x * QB + wid * 32;

    const short8 av = Qf[(size_t)(qbase >> 5) * 64 + lane];

    // C = a^2 broadcast along rows (row = (r&3) + 8*(r>>2) + 4*(lane>>5))
    f32x16 pc;
    {
        const int rb = qbase + 4 * (lane >> 5);
#pragma unroll
        for (int r = 0; r < 16; ++r) pc[r] = a2[rb + (r & 3) + 8 * (r >> 2)];
    }

    float rmin[16];
#pragma unroll
    for (int r = 0; r < 16; ++r) rmin[r] = 1e30f;

    const int nch = (t1 - t0 + CH - 1) / CH;

    // prologue: stage chunk 0 (CH*64 = 512 elems, 2 per thread)
    {
        const int elems = min(CH, t1 - t0) * 64;
        if (tid       < elems) sb[0][tid      ] = Sf[(size_t)t0*64 + tid      ];
        if (tid + 256 < elems) sb[0][tid + 256] = Sf[(size_t)t0*64 + tid + 256];
    }
    __syncthreads();

    int cur = 0;
    for (int ch = 0; ch < nch; ++ch) {
        const int tb = t0 + ch*CH;
        const int cnt = min(CH, t1 - tb);

        // issue next chunk's global loads EARLY (hide under MFMA phase)
        short8 st0, st1;
        bool sv0=false, sv1=false;
        if (ch + 1 < nch) {
            const int nb = tb + CH;
            const int nel = min(CH, t1 - nb) * 64;
            const size_t gb = (size_t)nb * 64;
            if (tid       < nel) { st0 = Sf[gb + tid      ]; sv0 = true; }
            if (tid + 256 < nel) { st1 = Sf[gb + tid + 256]; sv1 = true; }
        }

        int t = 0;
        for (; t + 2 <= cnt; t += 2) {
            const short8 b0 = sb[cur][t*64 + lane];
            const short8 b1 = sb[cur][t*64 + 64 + lane];
            const f32x16 c0 = __builtin_amdgcn_mfma_f32_32x32x16_bf16(av, b0, pc, 0, 0, 0);
            const f32x16 c1 = __builtin_amdgcn_mfma_f32_32x32x16_bf16(av, b1, pc, 0, 0, 0);
#pragma unroll
            for (int r = 0; r < 16; ++r)
                rmin[r] = fminf(fminf(rmin[r], c0[r]), c1[r]);  // v_min3
        }
        if (t < cnt) {
            const short8 b0 = sb[cur][t*64 + lane];
            const f32x16 c0 = __builtin_amdgcn_mfma_f32_32x32x16_bf16(av, b0, pc, 0, 0, 0);
#pragma unroll
            for (int r = 0; r < 16; ++r) rmin[r] = fminf(rmin[r], c0[r]);
        }

        if (ch + 1 < nch) {  // write-late into the other buffer
            if (sv0) sb[cur^1][tid      ] = st0;
            if (sv1) sb[cur^1][tid + 256] = st1;
        }
        __syncthreads();
        cur ^= 1;
    }

    // min over the 32 columns: 4 DPP steps (VALU) -> 16-group min in every
    // lane, then one xor16 shuffle -> 32-col min (stays within lane-half).
#pragma unroll
    for (int r = 0; r < 16; ++r) {
        float v = rmin[r];
        v = dppmin(v, 0xB1);
        v = dppmin(v, 0x4E);
        v = dppmin(v, 0x141);
        v = dppmin(v, 0x140);
        v = fminf(v, __shfl_xor(v, 16, 64));
        rmin[r] = v;
    }

    if ((lane & 31) == 0) {
        const int rb = qbase + 4 * (lane >> 5);
#pragma unroll
        for (int r = 0; r < 16; ++r) {
            const int qi = rb + (r & 3) + 8 * (r >> 2);
            if (qi < nq) {
                const float sq = fmaxf(rmin[r], 0.f);   // a^2 already inside
                atomicMin(&outb[qi], __float_as_uint(sq));
            }
        }
    }
}

__global__ __launch_bounds__(THREADS) void cd_reduce1(
    const uint32* __restrict__ bits, int count, double* __restrict__ partials)
{
    double s = 0.0;
    for (int i = blockIdx.x * THREADS + threadIdx.x; i < count; i += gridDim.x * THREADS)
        s += (double)sqrtf(__uint_as_float(bits[i]));
#pragma unroll
    for (int off = 32; off; off >>= 1) s += __shfl_down(s, off, 64);
    __shared__ double sw[4];
    const int lane = threadIdx.x & 63, wid = threadIdx.x >> 6;
    if (lane == 0) sw[wid] = s;
    __syncthreads();
    if (threadIdx.x == 0) partials[blockIdx.x] = sw[0] + sw[1] + sw[2] + sw[3];
}

__global__ __launch_bounds__(THREADS) void cd_reduce2(
    const double* __restrict__ partials, int nb, int total, float* __restrict__ out)
{
    double s = 0.0;
    for (int i = threadIdx.x; i < nb; i += THREADS) s += partials[i];
#pragma unroll
    for (int off = 32; off; off >>= 1) s += __shfl_down(s, off, 64);
    __shared__ double sw[4];
    const int lane = threadIdx.x & 63, wid = threadIdx.x >> 6;
    if (lane == 0) sw[wid] = s;
    __syncthreads();
    if (threadIdx.x == 0)
        out[0] = (float)((sw[0] + sw[1] + sw[2] + sw[3]) / (double)total);
}

extern "C" void kernel_launch(void* const* d_in, const int* in_sizes, int n_in,
                              void* d_out, int out_size, void* d_ws, size_t ws_size,
                              hipStream_t stream) {
    const float* a = (const float*)d_in[0];
    const float* b = (const float*)d_in[1];
    const int n = in_sizes[0] / 3;
    const int m = in_sizes[1] / 3;
    const int total = n + m;
    float* out = (float*)d_out;

    const int padN = (n + QB - 1) / QB * QB;
    const int padM = (m + QB - 1) / QB * QB;

    // ws: QfA | SfA | a2A | QfB | SfB | a2B | bits | partials
    char* wp = (char*)d_ws;
    short8* QfA = (short8*)wp;   wp += (size_t)padN * 64;
    short8* SfA = (short8*)wp;   wp += (size_t)padN * 64;
    float*  a2A = (float*)wp;    wp += (size_t)padN * 4;
    short8* QfB = (short8*)wp;   wp += (size_t)padM * 64;
    short8* SfB = (short8*)wp;   wp += (size_t)padM * 64;
    float*  a2B = (float*)wp;    wp += (size_t)padM * 4;
    uint32* bits = (uint32*)wp;  wp += (size_t)total * 4;
    wp = (char*)(((size_t)wp + 255) & ~(size_t)255);
    double* partials = (double*)wp;

    const int prepElems = max(max(padN, padM), total);
    cd_prep<<<(prepElems + THREADS - 1) / THREADS, THREADS, 0, stream>>>(
        a, n, padN, b, m, padM, QfA, SfA, a2A, QfB, SfB, a2B, bits);

    const int gx = max(padN, padM) / QB;
    dim3 grid(gx, JS, 2);
    cd_mfma<<<grid, THREADS, 0, stream>>>(QfA, SfA, a2A, padN, n,
                                          QfB, SfB, a2B, padM, m, bits);

    cd_reduce1<<<RB, THREADS, 0, stream>>>(bits, total, partials);
    cd_reduce2<<<1, THREADS, 0, stream>>>(partials, RB, total, out);
}